// Round 2
// baseline (1716.632 us; speedup 1.0000x reference)
//
#include <hip/hip_runtime.h>
#include <hip/hip_bf16.h>
#include <stdint.h>

// Problem constants
#define TOKENS 8192
#define IN_F   4096
#define OUT_F  11008

// GEMM tiling (m97 structure: 128x128 tile, BK=32, 4 waves 2x2, 4x4 frags/wave)
#define BM 128
#define BN 128
#define BK 32

typedef __attribute__((ext_vector_type(8))) short bf16x8;   // 8 bf16 = 4 VGPRs
typedef __attribute__((ext_vector_type(4))) float f32x4;    // MFMA 16x16 acc

typedef __attribute__((address_space(1))) void* gas1_t;
typedef __attribute__((address_space(3))) void* las3_t;

__device__ __forceinline__ void load_lds16(const void* g, void* l) {
  // async global->LDS, 16B per lane; LDS dest is wave-uniform base + lane*16
  __builtin_amdgcn_global_load_lds((gas1_t)(void*)g, (las3_t)l, 16, 0, 0);
}

// ---------------------------------------------------------------------------
// fp32 -> bf16 conversion (vectorized: 2x float4 in, 16B out per iter)
// ---------------------------------------------------------------------------
__global__ __launch_bounds__(256) void cvt_f32_bf16(
    const float* __restrict__ in, __hip_bfloat16* __restrict__ out, int n8) {
  int stride = gridDim.x * blockDim.x;
  for (int i = blockIdx.x * blockDim.x + threadIdx.x; i < n8; i += stride) {
    const float4* p = (const float4*)in + (size_t)i * 2;
    float4 v0 = p[0];
    float4 v1 = p[1];
    union { bf16x8 v; __hip_bfloat16 h[8]; } u;
    u.h[0] = __float2bfloat16(v0.x); u.h[1] = __float2bfloat16(v0.y);
    u.h[2] = __float2bfloat16(v0.z); u.h[3] = __float2bfloat16(v0.w);
    u.h[4] = __float2bfloat16(v1.x); u.h[5] = __float2bfloat16(v1.y);
    u.h[6] = __float2bfloat16(v1.z); u.h[7] = __float2bfloat16(v1.w);
    ((bf16x8*)out)[i] = u.v;
  }
}

// ---------------------------------------------------------------------------
// bf16 MFMA GEMM: C[M][N] = A[M][K] * B[N][K]^T * s + bias
// m97 structure: 128x128 tile, BK=32, double-buffered LDS via global_load_lds,
// one barrier per K-step.
// ---------------------------------------------------------------------------
__global__ __launch_bounds__(256, 2) void gemm_bf16(
    const __hip_bfloat16* __restrict__ A,   // [TOKENS][IN_F]
    const __hip_bfloat16* __restrict__ B,   // [OUT_F][IN_F]  (= B^T layout)
    const float* __restrict__ in_scale,
    const float* __restrict__ w_scale,
    const float* __restrict__ bias,
    float* __restrict__ out)                // [TOKENS][OUT_F]
{
  __shared__ __hip_bfloat16 As[2][BM * BK];
  __shared__ __hip_bfloat16 Bs[2][BN * BK];

  const int tid  = threadIdx.x;
  const int lane = tid & 63;
  const int wid  = tid >> 6;   // 0..3
  const int wr   = wid >> 1;   // wave row 0..1 (owns 64 rows)
  const int wc   = wid & 1;    // wave col 0..1 (owns 64 cols)

  const int brow = blockIdx.y * BM;
  const int bcol = blockIdx.x * BN;

  // staging lane mapping: 16 rows x 32 cols per 1KB instruction
  const int sr = lane >> 2;         // row within 16-row chunk
  const int sc = (lane & 3) * 8;    // bf16 col offset

  // fragment lane mapping (verified m89/m91): idx = lane&15, k = (lane>>4)*8+j
  const int fr = lane & 15;
  const int fk = (lane >> 4) * 8;

  f32x4 acc[4][4];
  #pragma unroll
  for (int i = 0; i < 4; ++i)
    #pragma unroll
    for (int j = 0; j < 4; ++j)
      acc[i][j] = (f32x4)(0.f);

  auto stage = [&](int buf, int k0) {
    #pragma unroll
    for (int q = 0; q < 2; ++q) {
      const int r0 = wid * 32 + q * 16;   // wave-uniform
      load_lds16(A + (size_t)(brow + r0 + sr) * IN_F + k0 + sc,
                 &As[buf][r0 * BK]);
      load_lds16(B + (size_t)(bcol + r0 + sr) * IN_F + k0 + sc,
                 &Bs[buf][r0 * BK]);
    }
  };

  stage(0, 0);
  __syncthreads();   // drains vmcnt(0): prologue tile resident

  int buf = 0;
  const int NT = IN_F / BK;   // 128
  for (int kt = 0; kt < NT; ++kt) {
    if (kt + 1 < NT) stage(buf ^ 1, (kt + 1) * BK);

    bf16x8 a[4], b[4];
    #pragma unroll
    for (int i = 0; i < 4; ++i)
      a[i] = *(const bf16x8*)&As[buf][(wr * 64 + i * 16 + fr) * BK + fk];
    #pragma unroll
    for (int j = 0; j < 4; ++j)
      b[j] = *(const bf16x8*)&Bs[buf][(wc * 64 + j * 16 + fr) * BK + fk];

    #pragma unroll
    for (int i = 0; i < 4; ++i)
      #pragma unroll
      for (int j = 0; j < 4; ++j)
        acc[i][j] = __builtin_amdgcn_mfma_f32_16x16x32_bf16(a[i], b[j],
                                                            acc[i][j], 0, 0, 0);

    __syncthreads();  // drains vmcnt(0)+lgkmcnt(0): next tile staged, reads done
    buf ^= 1;
  }

  // epilogue: C/D layout col=lane&15, row=(lane>>4)*4+reg
  const float s = in_scale[0] * w_scale[0];
  #pragma unroll
  for (int j = 0; j < 4; ++j) {
    const int col = bcol + wc * 64 + j * 16 + fr;
    const float bj = bias[col];
    #pragma unroll
    for (int i = 0; i < 4; ++i) {
      const int row = brow + wr * 64 + i * 16 + (lane >> 4) * 4;
      #pragma unroll
      for (int r = 0; r < 4; ++r)
        out[(size_t)(row + r) * OUT_F + col] = acc[i][j][r] * s + bj;
    }
  }
}

// ---------------------------------------------------------------------------
// Fallback (only if ws_size is too small for bf16 copies): fp32 LDS-tiled GEMM
// ---------------------------------------------------------------------------
__global__ void gemm_fallback(
    const float* __restrict__ A, const float* __restrict__ B,
    const float* __restrict__ in_scale, const float* __restrict__ w_scale,
    const float* __restrict__ bias, float* __restrict__ out) {
  __shared__ float As[16][17], Bs[16][17];
  const int tx = threadIdx.x, ty = threadIdx.y;
  const int row = blockIdx.y * 16 + ty;
  const int col = blockIdx.x * 16 + tx;
  float acc = 0.f;
  for (int k0 = 0; k0 < IN_F; k0 += 16) {
    As[ty][tx] = A[(size_t)row * IN_F + k0 + tx];
    Bs[ty][tx] = B[(size_t)(blockIdx.x * 16 + ty) * IN_F + k0 + tx];
    __syncthreads();
    #pragma unroll
    for (int kk = 0; kk < 16; ++kk) acc += As[ty][kk] * Bs[tx][kk];
    __syncthreads();
  }
  out[(size_t)row * OUT_F + col] = acc * in_scale[0] * w_scale[0] + bias[col];
}

// ---------------------------------------------------------------------------
extern "C" void kernel_launch(void* const* d_in, const int* in_sizes, int n_in,
                              void* d_out, int out_size, void* d_ws, size_t ws_size,
                              hipStream_t stream) {
  const float* x    = (const float*)d_in[0];   // [8192][4096]
  const float* w    = (const float*)d_in[1];   // [11008][4096]
  const float* is   = (const float*)d_in[2];   // [1]
  const float* wsc  = (const float*)d_in[3];   // [1]
  const float* bias = (const float*)d_in[4];   // [11008]
  float* out = (float*)d_out;

  const size_t needA = (size_t)TOKENS * IN_F * sizeof(__hip_bfloat16);
  const size_t needB = (size_t)OUT_F * IN_F * sizeof(__hip_bfloat16);

  if (ws_size >= needA + needB) {
    __hip_bfloat16* Axb = (__hip_bfloat16*)d_ws;
    __hip_bfloat16* Bxb = (__hip_bfloat16*)((char*)d_ws + needA);

    cvt_f32_bf16<<<2048, 256, 0, stream>>>(x, Axb, (TOKENS * IN_F) / 8);
    cvt_f32_bf16<<<2048, 256, 0, stream>>>(w, Bxb, (OUT_F * IN_F) / 8);

    dim3 grid(OUT_F / BN, TOKENS / BM);   // 86 x 64 = 5504 blocks
    gemm_bf16<<<grid, 256, 0, stream>>>(Axb, Bxb, is, wsc, bias, out);
  } else {
    dim3 grid(OUT_F / 16, TOKENS / 16);
    dim3 block(16, 16);
    gemm_fallback<<<grid, block, 0, stream>>>(x, w, is, wsc, bias, out);
  }
}